// Round 2
// baseline (105.106 us; speedup 1.0000x reference)
//
#include <hip/hip_runtime.h>

#define BB 8
#define HH 256
#define LL 4096
#define STR 72          // LDS row stride in shorts

typedef __attribute__((ext_vector_type(8))) short short8;   // 8 bf16 = MFMA A/B frag
typedef __attribute__((ext_vector_type(4))) float f32x4;    // MFMA C/D frag

static __device__ inline unsigned short f2bf(float x) {
    union { float f; unsigned u; } v; v.f = x;
    unsigned r = v.u + 0x7fffu + ((v.u >> 16) & 1u);   // RNE
    return (unsigned short)(r >> 16);
}
static __device__ inline float bf2f(unsigned short us) {
    union { unsigned u; float f; } v; v.u = ((unsigned)us) << 16; return v.f;
}

#define CMUL(or_, oi_, ar_, ai_, br_, bi_) do { \
    float _tr = fmaf((ar_), (br_), -(ai_) * (bi_)); \
    float _ti = fmaf((ar_), (bi_), (ai_) * (br_)); \
    (or_) = _tr; (oi_) = _ti; } while (0)

// One block per (b,h): 2048 blocks, single 64x64 tile each, 5-barrier pipeline.
// H (Toeplitz) is never staged: aH frags are built per-lane from the shared
// h[0..63] vector. P and R are built in LDS during precompute (pre-B1) and
// consumed as register frags immediately after B1.
__global__ __launch_bounds__(256, 4) void s4_fused_kernel(
    const float* __restrict__ u, const float* __restrict__ theta,
    const float* __restrict__ a, const float* __restrict__ Dp,
    const float* __restrict__ b_p, const float* __restrict__ c_p,
    const float* __restrict__ x0, float* __restrict__ out)
{
    const int tid = threadIdx.x;
    const int blk = blockIdx.x;           // 2048
    const int hh  = blk >> 3;
    const int b   = blk & 7;

    __shared__ __align__(16) short Us[64 * STR];    // u tile (bf16), [chunk][time]
    __shared__ __align__(16) short Pm[64 * STR];    // Pmat (planar powers)
    __shared__ __align__(16) short EQ[64 * STR];    // Rmat -> E -> Q
    __shared__ __align__(16) float Seg[32 * 18];
    __shared__ unsigned short h_sb[64];

    const int d    = tid & 31;
    const int kb   = tid >> 5;
    const int g    = tid >> 5;
    const int ln   = tid & 63;
    const int m0   = (tid >> 6) << 4;
    const int rowi = ln & 15;
    const int quad = ln >> 4;

    // ---- issue u loads first (HBM latency hides under precompute) ----
    const float* up = u + ((((size_t)b * HH) + hh) << 12);
    float4 v0[4];
    #pragma unroll
    for (int jj = 0; jj < 4; ++jj)
        v0[jj] = ((const float4*)up)[tid + (jj << 8)];

    // ---- per-h precompute (identical math to verified kernel) ----
    const float T = 1.0f / (LL - 1);
    const float lr = a[hh * 32 + d];
    const float li = theta[hh * 32 + d];
    float sn, cS;
    sincosf(li * T, &sn, &cS);
    const float er = expf(lr * T);
    const float Rr = er * cS, Ri = er * sn;      // r = exp(ls*T)
    const float den = lr * lr + li * li;
    const float t0r = ((Rr - 1.f) * lr + Ri * li) / den;
    const float t0i = (Ri * lr - (Rr - 1.f) * li) / den;
    const float qq  = b_p[hh * 32 + d] * c_p[hh * 32 + d];
    const float wre = 2.f * qq * t0r, wim = 2.f * qq * t0i;
    const float vv  = 4.f * T * c_p[hh * 32 + d] * x0[hh * 32 + d];
    const float Dh  = Dp[hh];

    float r2r, r2i, r4r, r4i, r8r, r8i, r16r, r16i, r32r, r32i;
    CMUL(r2r, r2i, Rr, Ri, Rr, Ri);
    CMUL(r4r, r4i, r2r, r2i, r2r, r2i);
    CMUL(r8r, r8i, r4r, r4i, r4r, r4i);
    CMUL(r16r, r16i, r8r, r8i, r8r, r8i);
    CMUL(r32r, r32i, r16r, r16i, r16r, r16i);

    {   // fill Rmat(EQ), Pmat(Pm); reduce h -> h_sb (bf16)
        float pr = 1.f, pi = 0.f;
        if (kb & 1) CMUL(pr, pi, pr, pi, r8r, r8i);
        if (kb & 2) CMUL(pr, pi, pr, pi, r16r, r16i);
        if (kb & 4) CMUL(pr, pi, pr, pi, r32r, r32i);
        #pragma unroll
        for (int k8 = 0; k8 < 8; ++k8) {
            const int k = (kb << 3) + k8;
            EQ[k * STR + d]            = (short)f2bf(pr);
            EQ[k * STR + 32 + d]       = (short)f2bf(-pi);
            Pm[d * STR + (63 - k)]        = (short)f2bf(pr);
            Pm[(32 + d) * STR + (63 - k)] = (short)f2bf(pi);
            float hk = fmaf(wre, pr, -wim * pi);     // Re(w * r^k)
            hk += __shfl_xor(hk, 1);
            hk += __shfl_xor(hk, 2);
            hk += __shfl_xor(hk, 4);
            hk += __shfl_xor(hk, 8);
            hk += __shfl_xor(hk, 16);
            if (d == 0) h_sb[k] = f2bf(hk);
            CMUL(pr, pi, pr, pi, Rr, Ri);
        }
    }

    // A = r^64, w*r, A^8 / A^16 / A^32 (registers)
    float Ar, Ai, wrr, wri;
    CMUL(Ar, Ai, r32r, r32i, r32r, r32i);
    CMUL(wrr, wri, wre, wim, Rr, Ri);
    float S8r, S8i, S16r, S16i, S32r, S32i;
    {
        float b1r, b1i, b2r, b2i;
        CMUL(b1r, b1i, Ar, Ai, Ar, Ai);
        CMUL(b2r, b2i, b1r, b1i, b1r, b1i);
        CMUL(S8r, S8i, b2r, b2i, b2r, b2i);
        CMUL(S16r, S16i, S8r, S8i, S8r, S8i);
        CMUL(S32r, S32i, S16r, S16i, S16r, S16i);
    }
    __syncthreads();                               // B1: Rmat/Pmat/h ready

    // ---- frags: aP/aR from LDS, aH straight from h vector ----
    short8 aH[2], aP[2], aR[2];
    #pragma unroll
    for (int kh = 0; kh < 2; ++kh) {
        const int off = (m0 + rowi) * STR + (kh << 5) + (quad << 3);
        aP[kh] = *(const short8*)&Pm[off];
        aR[kh] = *(const short8*)&EQ[off];
    }
    #pragma unroll
    for (int kh = 0; kh < 2; ++kh) {
        short8 hv;
        #pragma unroll
        for (int j = 0; j < 8; ++j) {
            const int dt = (m0 + rowi) - ((kh << 5) + (quad << 3) + j);
            hv[j] = (dt >= 0) ? (short)h_sb[dt] : (short)0;
        }
        aH[kh] = hv;
    }

    // ---- stage u -> Us ----
    #pragma unroll
    for (int jj = 0; jj < 4; ++jj) {
        const int v  = tid + (jj << 8);
        const int c  = v >> 4;
        const int t0 = (v & 15) << 2;
        uint2 pk;
        pk.x = (unsigned)f2bf(v0[jj].x) | ((unsigned)f2bf(v0[jj].y) << 16);
        pk.y = (unsigned)f2bf(v0[jj].z) | ((unsigned)f2bf(v0[jj].w) << 16);
        *(uint2*)&Us[c * STR + t0] = pk;
    }
    __syncthreads();                               // B2: Us ready, frag reads done

    // ---- mm1 (Y1 = H x U) + mm2 (E = P x U) ----
    f32x4 accY[4], accE[4];
    #pragma unroll
    for (int nt = 0; nt < 4; ++nt) {
        accY[nt] = (f32x4){0.f, 0.f, 0.f, 0.f};
        accE[nt] = (f32x4){0.f, 0.f, 0.f, 0.f};
    }
    #pragma unroll
    for (int kh = 0; kh < 2; ++kh) {
        const int k0 = kh << 5;
        #pragma unroll
        for (int nt = 0; nt < 4; ++nt) {
            const short8 bU = *(const short8*)&Us[((nt << 4) + rowi) * STR + k0 + (quad << 3)];
            accY[nt] = __builtin_amdgcn_mfma_f32_16x16x32_bf16(aH[kh], bU, accY[nt], 0, 0, 0);
            accE[nt] = __builtin_amdgcn_mfma_f32_16x16x32_bf16(aP[kh], bU, accE[nt], 0, 0, 0);
        }
    }

    // ---- write E planar (overwrites Rmat; aR already in regs) ----
    #pragma unroll
    for (int nt = 0; nt < 4; ++nt) {
        uint2 pk;
        pk.x = (unsigned)f2bf(accE[nt][0]) | ((unsigned)f2bf(accE[nt][1]) << 16);
        pk.y = (unsigned)f2bf(accE[nt][2]) | ((unsigned)f2bf(accE[nt][3]) << 16);
        *(uint2*)&EQ[((nt << 4) + rowi) * STR + m0 + (quad << 2)] = pk;
    }
    __syncthreads();                               // B3: E ready

    // ---- scan phase a: thread (d,g) owns chunks 8g..8g+7 ----
    const int cb = g << 3;
    float Er[8], Ei[8];
    {
        float Sr = 0.f, Si = 0.f;
        #pragma unroll
        for (int i = 0; i < 8; ++i) {
            const int c = cb + i;
            Er[i] = bf2f((unsigned short)EQ[c * STR + d]);
            Ei[i] = bf2f((unsigned short)EQ[c * STR + 32 + d]);
            const float nr = fmaf(Ar, Sr, fmaf(-Ai, Si, Er[i]));
            const float ni = fmaf(Ar, Si, fmaf(Ai, Sr, Ei[i]));
            Sr = nr; Si = ni;
        }
        Seg[d * 18 + (g << 1)]     = Sr;
        Seg[d * 18 + (g << 1) + 1] = Si;
    }
    __syncthreads();                               // B4: Seg ready

    // ---- scan phase c: combine + emit Q ----
    {
        float offr = 0.f, offi = 0.f;
        #pragma unroll
        for (int gp = 0; gp < 7; ++gp) {
            const float2 sg = *(const float2*)&Seg[d * 18 + (gp << 1)];
            const float nr = fmaf(S8r, offr, fmaf(-S8i, offi, sg.x));
            const float ni = fmaf(S8r, offi, fmaf(S8i, offr, sg.y));
            const bool take = gp < g;
            offr = take ? nr : offr;
            offi = take ? ni : offi;
        }
        float Gr = vv, Gi = 0.f;               // v * A^(8g)
        if (g & 1) { float nr, ni; CMUL(nr, ni, Gr, Gi, S8r, S8i);   Gr = nr; Gi = ni; }
        if (g & 2) { float nr, ni; CMUL(nr, ni, Gr, Gi, S16r, S16i); Gr = nr; Gi = ni; }
        if (g & 4) { float nr, ni; CMUL(nr, ni, Gr, Gi, S32r, S32i); Gr = nr; Gi = ni; }
        float Sr = offr, Si = offi;
        #pragma unroll
        for (int i = 0; i < 8; ++i) {
            const int c = cb + i;
            const float Qr = fmaf(wrr, Sr, fmaf(-wri, Si, Gr));
            const float Qi = fmaf(wrr, Si, fmaf(wri, Sr, Gi));
            EQ[c * STR + d]      = (short)f2bf(Qr);
            EQ[c * STR + 32 + d] = (short)f2bf(Qi);
            const float nr = fmaf(Ar, Sr, fmaf(-Ai, Si, Er[i]));
            const float ni = fmaf(Ar, Si, fmaf(Ai, Sr, Ei[i]));
            Sr = nr; Si = ni;
            float nGr, nGi;
            CMUL(nGr, nGi, Ar, Ai, Gr, Gi);
            Gr = nGr; Gi = nGi;
        }
    }
    __syncthreads();                               // B5: Q ready

    // ---- mm3: Y += R x Q ----
    #pragma unroll
    for (int kh = 0; kh < 2; ++kh) {
        const int k0 = kh << 5;
        #pragma unroll
        for (int nt = 0; nt < 4; ++nt) {
            const short8 bQ = *(const short8*)&EQ[((nt << 4) + rowi) * STR + k0 + (quad << 3)];
            accY[nt] = __builtin_amdgcn_mfma_f32_16x16x32_bf16(aR[kh], bQ, accY[nt], 0, 0, 0);
        }
    }

    // ---- epilogue: += D*u (from LDS tile), float4 stores ----
    float* op = out + ((((size_t)b * HH) + hh) << 12);
    #pragma unroll
    for (int nt = 0; nt < 4; ++nt) {
        const int c    = (nt << 4) + rowi;
        const int toff = m0 + (quad << 2);
        const uint2 uu = *(const uint2*)&Us[c * STR + toff];
        float4 res;
        res.x = fmaf(Dh, bf2f((unsigned short)(uu.x & 0xffffu)), accY[nt][0]);
        res.y = fmaf(Dh, bf2f((unsigned short)(uu.x >> 16)),     accY[nt][1]);
        res.z = fmaf(Dh, bf2f((unsigned short)(uu.y & 0xffffu)), accY[nt][2]);
        res.w = fmaf(Dh, bf2f((unsigned short)(uu.y >> 16)),     accY[nt][3]);
        *(float4*)&op[c * 64 + toff] = res;
    }
}

extern "C" void kernel_launch(void* const* d_in, const int* in_sizes, int n_in,
                              void* d_out, int out_size, void* d_ws, size_t ws_size,
                              hipStream_t stream) {
    const float* u     = (const float*)d_in[0];
    const float* theta = (const float*)d_in[1];
    const float* a     = (const float*)d_in[2];
    const float* Dp    = (const float*)d_in[3];
    const float* b_p   = (const float*)d_in[4];
    const float* c_p   = (const float*)d_in[5];
    const float* x0    = (const float*)d_in[6];
    float* out = (float*)d_out;
    (void)d_ws; (void)ws_size;

    hipLaunchKernelGGL(s4_fused_kernel, dim3(BB * HH), dim3(256), 0, stream,
                       u, theta, a, Dp, b_p, c_p, x0, out);
}

// Round 3
// 101.276 us; speedup vs baseline: 1.0378x; 1.0378x over previous
//
#include <hip/hip_runtime.h>

#define BB 8
#define HH 256
#define LL 4096
#define STR 72          // LDS row stride in shorts

typedef __attribute__((ext_vector_type(8))) short short8;   // 8 bf16 = MFMA A/B frag
typedef __attribute__((ext_vector_type(4))) float f32x4;    // MFMA C/D frag

static __device__ inline unsigned short f2bf(float x) {
    union { float f; unsigned u; } v; v.f = x;
    unsigned r = v.u + 0x7fffu + ((v.u >> 16) & 1u);   // RNE
    return (unsigned short)(r >> 16);
}
static __device__ inline float bf2f(unsigned short us) {
    union { unsigned u; float f; } v; v.u = ((unsigned)us) << 16; return v.f;
}

#define CMUL(or_, oi_, ar_, ai_, br_, bi_) do { \
    float _tr = fmaf((ar_), (br_), -(ai_) * (bi_)); \
    float _ti = fmaf((ar_), (bi_), (ai_) * (br_)); \
    (or_) = _tr; (oi_) = _ti; } while (0)

// One block per (h, b-pair): 1024 blocks, two 64x64 tiles pipelined.
// vs R1: Toeplitz H is never staged (aH built per-lane from h_sb), removing
// one LDS fill phase + 2 barriers; tile0 staging overlaps precompute.
// 9 barriers total per block.
__global__ __launch_bounds__(256, 4) void s4_fused_kernel(
    const float* __restrict__ u, const float* __restrict__ theta,
    const float* __restrict__ a, const float* __restrict__ Dp,
    const float* __restrict__ b_p, const float* __restrict__ c_p,
    const float* __restrict__ x0, float* __restrict__ out)
{
    const int tid = threadIdx.x;
    const int blk = blockIdx.x;           // 1024
    const int hh  = blk >> 2;
    const int bp  = blk & 3;              // handles b = 2bp, 2bp+1

    __shared__ __align__(16) short UsA[64 * STR];   // u tile 0
    __shared__ __align__(16) short UsB[64 * STR];   // precompute: Pmat -> u tile 1
    __shared__ __align__(16) short EQ[64 * STR];    // precompute: Rmat -> E -> Q
    __shared__ __align__(16) float Seg[32 * 18];
    __shared__ unsigned short h_sb[64];

    const int d    = tid & 31;
    const int g    = tid >> 5;            // also the kb of the precompute fill
    const int ln   = tid & 63;
    const int m0   = (tid >> 6) << 4;
    const int rowi = ln & 15;
    const int quad = ln >> 4;

    // ---- issue tile0 u loads first (HBM latency hides under precompute) ----
    const float* up0 = u + ((((size_t)(bp * 2) * HH) + hh) << 12);
    const float* up1 = u + ((((size_t)(bp * 2 + 1) * HH) + hh) << 12);
    float4 v0[4];
    #pragma unroll
    for (int jj = 0; jj < 4; ++jj)
        v0[jj] = ((const float4*)up0)[tid + (jj << 8)];

    // ---- per-h precompute (identical math to verified kernels) ----
    const float T = 1.0f / (LL - 1);
    const float lr = a[hh * 32 + d];
    const float li = theta[hh * 32 + d];
    float sn, cS;
    sincosf(li * T, &sn, &cS);
    const float er = expf(lr * T);
    const float Rr = er * cS, Ri = er * sn;      // r = exp(ls*T)
    const float den = lr * lr + li * li;
    const float t0r = ((Rr - 1.f) * lr + Ri * li) / den;
    const float t0i = (Ri * lr - (Rr - 1.f) * li) / den;
    const float qq  = b_p[hh * 32 + d] * c_p[hh * 32 + d];
    const float wre = 2.f * qq * t0r, wim = 2.f * qq * t0i;
    const float vv  = 4.f * T * c_p[hh * 32 + d] * x0[hh * 32 + d];
    const float Dh  = Dp[hh];

    float r2r, r2i, r4r, r4i, r8r, r8i, r16r, r16i, r32r, r32i;
    CMUL(r2r, r2i, Rr, Ri, Rr, Ri);
    CMUL(r4r, r4i, r2r, r2i, r2r, r2i);
    CMUL(r8r, r8i, r4r, r4i, r4r, r4i);
    CMUL(r16r, r16i, r8r, r8i, r8r, r8i);
    CMUL(r32r, r32i, r16r, r16i, r16r, r16i);

    {   // fill Rmat(EQ), Pmat(UsB); reduce h -> h_sb (bf16)
        float pr = 1.f, pi = 0.f;
        if (g & 1) CMUL(pr, pi, pr, pi, r8r, r8i);
        if (g & 2) CMUL(pr, pi, pr, pi, r16r, r16i);
        if (g & 4) CMUL(pr, pi, pr, pi, r32r, r32i);
        #pragma unroll
        for (int k8 = 0; k8 < 8; ++k8) {
            const int k = (g << 3) + k8;
            EQ[k * STR + d]            = (short)f2bf(pr);
            EQ[k * STR + 32 + d]       = (short)f2bf(-pi);
            UsB[d * STR + (63 - k)]        = (short)f2bf(pr);
            UsB[(32 + d) * STR + (63 - k)] = (short)f2bf(pi);
            float hk = fmaf(wre, pr, -wim * pi);     // Re(w * r^k)
            hk += __shfl_xor(hk, 1);
            hk += __shfl_xor(hk, 2);
            hk += __shfl_xor(hk, 4);
            hk += __shfl_xor(hk, 8);
            hk += __shfl_xor(hk, 16);
            if (d == 0) h_sb[k] = f2bf(hk);
            CMUL(pr, pi, pr, pi, Rr, Ri);
        }
    }

    // A = r^64, w*r, A^8 / A^16 / A^32 (registers)
    float Ar, Ai, wrr, wri;
    CMUL(Ar, Ai, r32r, r32i, r32r, r32i);
    CMUL(wrr, wri, wre, wim, Rr, Ri);
    float S8r, S8i, S16r, S16i, S32r, S32i;
    {
        float b1r, b1i, b2r, b2i;
        CMUL(b1r, b1i, Ar, Ai, Ar, Ai);
        CMUL(b2r, b2i, b1r, b1i, b1r, b1i);
        CMUL(S8r, S8i, b2r, b2i, b2r, b2i);
        CMUL(S16r, S16i, S8r, S8i, S8r, S8i);
        CMUL(S32r, S32i, S16r, S16i, S16r, S16i);
    }

    // ---- stage tile0 -> UsA (independent buffer, overlaps precompute) ----
    #pragma unroll
    for (int jj = 0; jj < 4; ++jj) {
        const int v  = tid + (jj << 8);
        const int c  = v >> 4;
        const int t0 = (v & 15) << 2;
        uint2 pk;
        pk.x = (unsigned)f2bf(v0[jj].x) | ((unsigned)f2bf(v0[jj].y) << 16);
        pk.y = (unsigned)f2bf(v0[jj].z) | ((unsigned)f2bf(v0[jj].w) << 16);
        *(uint2*)&UsA[c * STR + t0] = pk;
    }
    // ---- issue tile1 loads (drained into UsB during tile0 compute) ----
    float4 v1[4];
    #pragma unroll
    for (int jj = 0; jj < 4; ++jj)
        v1[jj] = ((const float4*)up1)[tid + (jj << 8)];
    __syncthreads();                               // B1: Rmat/Pmat/h_sb/UsA ready

    // ---- frags: aP/aR from LDS, aH built from h_sb ----
    short8 aH[2], aP[2], aR[2];
    #pragma unroll
    for (int kh = 0; kh < 2; ++kh) {
        const int off = (m0 + rowi) * STR + (kh << 5) + (quad << 3);
        aP[kh] = *(const short8*)&UsB[off];
        aR[kh] = *(const short8*)&EQ[off];
    }
    #pragma unroll
    for (int kh = 0; kh < 2; ++kh) {
        short8 hv;
        #pragma unroll
        for (int j = 0; j < 8; ++j) {
            const int dt = (m0 + rowi) - ((kh << 5) + (quad << 3) + j);
            hv[j] = (dt >= 0) ? (short)h_sb[dt] : (short)0;
        }
        aH[kh] = hv;
    }
    __syncthreads();                               // B2: frag reads done; UsB/EQ free

    #pragma unroll
    for (int it = 0; it < 2; ++it) {
        short* Us = it ? UsB : UsA;

        // ---- mm1 (Y1 = H x U) + mm2 (E = P x U), A-frags from regs ----
        f32x4 accY[4], accE[4];
        #pragma unroll
        for (int nt = 0; nt < 4; ++nt) {
            accY[nt] = (f32x4){0.f, 0.f, 0.f, 0.f};
            accE[nt] = (f32x4){0.f, 0.f, 0.f, 0.f};
        }
        #pragma unroll
        for (int kh = 0; kh < 2; ++kh) {
            const int k0 = kh << 5;
            #pragma unroll
            for (int nt = 0; nt < 4; ++nt) {
                const short8 bU = *(const short8*)&Us[((nt << 4) + rowi) * STR + k0 + (quad << 3)];
                accY[nt] = __builtin_amdgcn_mfma_f32_16x16x32_bf16(aH[kh], bU, accY[nt], 0, 0, 0);
                accE[nt] = __builtin_amdgcn_mfma_f32_16x16x32_bf16(aP[kh], bU, accE[nt], 0, 0, 0);
            }
        }

        // ---- write E planar ----
        #pragma unroll
        for (int nt = 0; nt < 4; ++nt) {
            uint2 pk;
            pk.x = (unsigned)f2bf(accE[nt][0]) | ((unsigned)f2bf(accE[nt][1]) << 16);
            pk.y = (unsigned)f2bf(accE[nt][2]) | ((unsigned)f2bf(accE[nt][3]) << 16);
            *(uint2*)&EQ[((nt << 4) + rowi) * STR + m0 + (quad << 2)] = pk;
        }

        // ---- drain tile1 prefetch into UsB (covered by tile0 compute) ----
        if (it == 0) {
            #pragma unroll
            for (int jj = 0; jj < 4; ++jj) {
                const int v  = tid + (jj << 8);
                const int c  = v >> 4;
                const int t0 = (v & 15) << 2;
                uint2 pk;
                pk.x = (unsigned)f2bf(v1[jj].x) | ((unsigned)f2bf(v1[jj].y) << 16);
                pk.y = (unsigned)f2bf(v1[jj].z) | ((unsigned)f2bf(v1[jj].w) << 16);
                *(uint2*)&UsB[c * STR + t0] = pk;
            }
        }
        __syncthreads();                           // B3/B7: E ready (UsB staged)

        // ---- scan phase a: thread (d,g) owns chunks 8g..8g+7 ----
        const int cb = g << 3;
        float Er[8], Ei[8];
        {
            float Sr = 0.f, Si = 0.f;
            #pragma unroll
            for (int i = 0; i < 8; ++i) {
                const int c = cb + i;
                Er[i] = bf2f((unsigned short)EQ[c * STR + d]);
                Ei[i] = bf2f((unsigned short)EQ[c * STR + 32 + d]);
                const float nr = fmaf(Ar, Sr, fmaf(-Ai, Si, Er[i]));
                const float ni = fmaf(Ar, Si, fmaf(Ai, Sr, Ei[i]));
                Sr = nr; Si = ni;
            }
            Seg[d * 18 + (g << 1)]     = Sr;
            Seg[d * 18 + (g << 1) + 1] = Si;
        }
        __syncthreads();                           // B4/B8: Seg ready

        // ---- scan phase c: combine + emit Q ----
        {
            float offr = 0.f, offi = 0.f;
            #pragma unroll
            for (int gp = 0; gp < 7; ++gp) {
                const float2 sg = *(const float2*)&Seg[d * 18 + (gp << 1)];
                const float nr = fmaf(S8r, offr, fmaf(-S8i, offi, sg.x));
                const float ni = fmaf(S8r, offi, fmaf(S8i, offr, sg.y));
                const bool take = gp < g;
                offr = take ? nr : offr;
                offi = take ? ni : offi;
            }
            float Gr = vv, Gi = 0.f;               // v * A^(8g)
            if (g & 1) { float nr, ni; CMUL(nr, ni, Gr, Gi, S8r, S8i);   Gr = nr; Gi = ni; }
            if (g & 2) { float nr, ni; CMUL(nr, ni, Gr, Gi, S16r, S16i); Gr = nr; Gi = ni; }
            if (g & 4) { float nr, ni; CMUL(nr, ni, Gr, Gi, S32r, S32i); Gr = nr; Gi = ni; }
            float Sr = offr, Si = offi;
            #pragma unroll
            for (int i = 0; i < 8; ++i) {
                const int c = cb + i;
                const float Qr = fmaf(wrr, Sr, fmaf(-wri, Si, Gr));
                const float Qi = fmaf(wrr, Si, fmaf(wri, Sr, Gi));
                EQ[c * STR + d]      = (short)f2bf(Qr);
                EQ[c * STR + 32 + d] = (short)f2bf(Qi);
                const float nr = fmaf(Ar, Sr, fmaf(-Ai, Si, Er[i]));
                const float ni = fmaf(Ar, Si, fmaf(Ai, Sr, Ei[i]));
                Sr = nr; Si = ni;
                float nGr, nGi;
                CMUL(nGr, nGi, Ar, Ai, Gr, Gi);
                Gr = nGr; Gi = nGi;
            }
        }
        __syncthreads();                           // B5/B9: Q ready

        // ---- mm3: Y += R x Q ----
        #pragma unroll
        for (int kh = 0; kh < 2; ++kh) {
            const int k0 = kh << 5;
            #pragma unroll
            for (int nt = 0; nt < 4; ++nt) {
                const short8 bQ = *(const short8*)&EQ[((nt << 4) + rowi) * STR + k0 + (quad << 3)];
                accY[nt] = __builtin_amdgcn_mfma_f32_16x16x32_bf16(aR[kh], bQ, accY[nt], 0, 0, 0);
            }
        }

        // ---- epilogue: += D*u (from LDS tile), float4 stores ----
        float* op = out + ((((size_t)(bp * 2 + it) * HH) + hh) << 12);
        #pragma unroll
        for (int nt = 0; nt < 4; ++nt) {
            const int c    = (nt << 4) + rowi;
            const int toff = m0 + (quad << 2);
            const uint2 uu = *(const uint2*)&Us[c * STR + toff];
            float4 res;
            res.x = fmaf(Dh, bf2f((unsigned short)(uu.x & 0xffffu)), accY[nt][0]);
            res.y = fmaf(Dh, bf2f((unsigned short)(uu.x >> 16)),     accY[nt][1]);
            res.z = fmaf(Dh, bf2f((unsigned short)(uu.y & 0xffffu)), accY[nt][2]);
            res.w = fmaf(Dh, bf2f((unsigned short)(uu.y >> 16)),     accY[nt][3]);
            *(float4*)&op[c * 64 + toff] = res;
        }
        if (it == 0) __syncthreads();              // B6: EQ free for next tile
    }
}

extern "C" void kernel_launch(void* const* d_in, const int* in_sizes, int n_in,
                              void* d_out, int out_size, void* d_ws, size_t ws_size,
                              hipStream_t stream) {
    const float* u     = (const float*)d_in[0];
    const float* theta = (const float*)d_in[1];
    const float* a     = (const float*)d_in[2];
    const float* Dp    = (const float*)d_in[3];
    const float* b_p   = (const float*)d_in[4];
    const float* c_p   = (const float*)d_in[5];
    const float* x0    = (const float*)d_in[6];
    float* out = (float*)d_out;
    (void)d_ws; (void)ws_size;

    hipLaunchKernelGGL(s4_fused_kernel, dim3(HH * 4), dim3(256), 0, stream,
                       u, theta, a, Dp, b_p, c_p, x0, out);
}

// Round 4
// 101.269 us; speedup vs baseline: 1.0379x; 1.0001x over previous
//
#include <hip/hip_runtime.h>

#define BB 8
#define HH 256
#define LL 4096
#define STR 72          // LDS row stride in shorts

typedef __attribute__((ext_vector_type(8))) short short8;   // 8 bf16 = MFMA A/B frag
typedef __attribute__((ext_vector_type(4))) float f32x4;    // MFMA C/D frag

static __device__ inline unsigned short f2bf(float x) {
    union { float f; unsigned u; } v; v.f = x;
    unsigned r = v.u + 0x7fffu + ((v.u >> 16) & 1u);   // RNE
    return (unsigned short)(r >> 16);
}
static __device__ inline float bf2f(unsigned short us) {
    union { unsigned u; float f; } v; v.u = ((unsigned)us) << 16; return v.f;
}

#define CMUL(or_, oi_, ar_, ai_, br_, bi_) do { \
    float _tr = fmaf((ar_), (br_), -(ai_) * (bi_)); \
    float _ti = fmaf((ar_), (bi_), (ai_) * (br_)); \
    (or_) = _tr; (oi_) = _ti; } while (0)

// One block per (h, b-pair): 1024 blocks, two 64x64 tiles pipelined.
// vs R3: Pmat is never staged in LDS (aP built per-lane from shuffled r'
// powers); the freed 9 KB becomes a dedicated E buffer (Em), which removes
// the two barriers (old B2/B6) that only existed to protect E/Q aliasing.
// 7 barriers total. LDS 39.3 KB/block -> still 4 blocks/CU.
__global__ __launch_bounds__(256, 4) void s4_fused_kernel(
    const float* __restrict__ u, const float* __restrict__ theta,
    const float* __restrict__ a, const float* __restrict__ Dp,
    const float* __restrict__ b_p, const float* __restrict__ c_p,
    const float* __restrict__ x0, float* __restrict__ out)
{
    const int tid = threadIdx.x;
    const int blk = blockIdx.x;           // 1024
    const int hh  = blk >> 2;
    const int bp  = blk & 3;              // handles b = 2bp, 2bp+1

    __shared__ __align__(16) short UsA[64 * STR];   // u tile 0
    __shared__ __align__(16) short UsB[64 * STR];   // u tile 1
    __shared__ __align__(16) short EQ[64 * STR];    // Rmat -> Q
    __shared__ __align__(16) short Em[64 * STR];    // E (dedicated)
    __shared__ __align__(16) float Seg[32 * 18];
    __shared__ unsigned short h_sb[64];

    const int d    = tid & 31;
    const int g    = tid >> 5;            // also the kb of the precompute fill
    const int ln   = tid & 63;
    const int m0   = (tid >> 6) << 4;
    const int rowi = ln & 15;
    const int quad = ln >> 4;

    // ---- issue tile0 u loads first (HBM latency hides under precompute) ----
    const float* up0 = u + ((((size_t)(bp * 2) * HH) + hh) << 12);
    const float* up1 = u + ((((size_t)(bp * 2 + 1) * HH) + hh) << 12);
    float4 v0[4];
    #pragma unroll
    for (int jj = 0; jj < 4; ++jj)
        v0[jj] = ((const float4*)up0)[tid + (jj << 8)];

    // ---- per-h precompute (identical math to verified kernels) ----
    const float T = 1.0f / (LL - 1);
    const float lr = a[hh * 32 + d];
    const float li = theta[hh * 32 + d];
    float sn, cS;
    sincosf(li * T, &sn, &cS);
    const float er = expf(lr * T);
    const float Rr = er * cS, Ri = er * sn;      // r = exp(ls*T)
    const float den = lr * lr + li * li;
    const float t0r = ((Rr - 1.f) * lr + Ri * li) / den;
    const float t0i = (Ri * lr - (Rr - 1.f) * li) / den;
    const float qq  = b_p[hh * 32 + d] * c_p[hh * 32 + d];
    const float wre = 2.f * qq * t0r, wim = 2.f * qq * t0i;
    const float vv  = 4.f * T * c_p[hh * 32 + d] * x0[hh * 32 + d];
    const float Dh  = Dp[hh];

    float r2r, r2i, r4r, r4i, r8r, r8i, r16r, r16i, r32r, r32i;
    CMUL(r2r, r2i, Rr, Ri, Rr, Ri);
    CMUL(r4r, r4i, r2r, r2i, r2r, r2i);
    CMUL(r8r, r8i, r4r, r4i, r4r, r4i);
    CMUL(r16r, r16i, r8r, r8i, r8r, r8i);
    CMUL(r32r, r32i, r16r, r16i, r16r, r16i);

    {   // fill Rmat(EQ); reduce h -> h_sb (bf16). (No Pmat fill anymore.)
        float pr = 1.f, pi = 0.f;
        if (g & 1) CMUL(pr, pi, pr, pi, r8r, r8i);
        if (g & 2) CMUL(pr, pi, pr, pi, r16r, r16i);
        if (g & 4) CMUL(pr, pi, pr, pi, r32r, r32i);
        #pragma unroll
        for (int k8 = 0; k8 < 8; ++k8) {
            const int k = (g << 3) + k8;
            EQ[k * STR + d]            = (short)f2bf(pr);
            EQ[k * STR + 32 + d]       = (short)f2bf(-pi);
            float hk = fmaf(wre, pr, -wim * pi);     // Re(w * r^k)
            hk += __shfl_xor(hk, 1);
            hk += __shfl_xor(hk, 2);
            hk += __shfl_xor(hk, 4);
            hk += __shfl_xor(hk, 8);
            hk += __shfl_xor(hk, 16);
            if (d == 0) h_sb[k] = f2bf(hk);
            CMUL(pr, pi, pr, pi, Rr, Ri);
        }
    }

    // A = r^64, w*r, A^8 / A^16 / A^32 (registers)
    float Ar, Ai, wrr, wri;
    CMUL(Ar, Ai, r32r, r32i, r32r, r32i);
    CMUL(wrr, wri, wre, wim, Rr, Ri);
    float S8r, S8i, S16r, S16i, S32r, S32i;
    {
        float b1r, b1i, b2r, b2i;
        CMUL(b1r, b1i, Ar, Ai, Ar, Ai);
        CMUL(b2r, b2i, b1r, b1i, b1r, b1i);
        CMUL(S8r, S8i, b2r, b2i, b2r, b2i);
        CMUL(S16r, S16i, S8r, S8i, S8r, S8i);
        CMUL(S32r, S32i, S16r, S16i, S16r, S16i);
    }

    // ---- stage tile0 -> UsA (independent buffer, overlaps precompute) ----
    #pragma unroll
    for (int jj = 0; jj < 4; ++jj) {
        const int v  = tid + (jj << 8);
        const int c  = v >> 4;
        const int t0 = (v & 15) << 2;
        uint2 pk;
        pk.x = (unsigned)f2bf(v0[jj].x) | ((unsigned)f2bf(v0[jj].y) << 16);
        pk.y = (unsigned)f2bf(v0[jj].z) | ((unsigned)f2bf(v0[jj].w) << 16);
        *(uint2*)&UsA[c * STR + t0] = pk;
    }
    // ---- issue tile1 loads (drained into UsB during tile0 compute) ----
    float4 v1[4];
    #pragma unroll
    for (int jj = 0; jj < 4; ++jj)
        v1[jj] = ((const float4*)up1)[tid + (jj << 8)];
    __syncthreads();                               // B1: Rmat/h_sb/UsA ready

    // ---- frags: aR from LDS, aH from h_sb, aP per-lane from shuffled r' ----
    short8 aH[2], aP[2], aR[2];
    #pragma unroll
    for (int kh = 0; kh < 2; ++kh) {
        const int off = (m0 + rowi) * STR + (kh << 5) + (quad << 3);
        aR[kh] = *(const short8*)&EQ[off];
    }
    #pragma unroll
    for (int kh = 0; kh < 2; ++kh) {
        short8 hv;
        #pragma unroll
        for (int j = 0; j < 8; ++j) {
            const int dt = (m0 + rowi) - ((kh << 5) + (quad << 3) + j);
            hv[j] = (dt >= 0) ? (short)h_sb[dt] : (short)0;
        }
        aH[kh] = hv;
    }
    {
        // Pmat[row][c] = row<32 ? Re(r_{row}^{63-c}) : Im(r_{row-32}^{63-c})
        // aP[kh][j] = Pmat[row][kh*32 + quad*8 + j]
        const int  row  = m0 + rowi;
        const int  dp   = row & 31;
        const bool isIm = row >= 32;
        const float R1r = __shfl(Rr,   dp), R1i = __shfl(Ri,   dp);
        const float P8r = __shfl(r8r,  dp), P8i = __shfl(r8i,  dp);
        const float P16r = __shfl(r16r, dp), P16i = __shfl(r16i, dp);
        const float P32r = __shfl(r32r, dp), P32i = __shfl(r32i, dp);
        #pragma unroll
        for (int kh = 0; kh < 2; ++kh) {
            const int col0 = (kh << 5) + (quad << 3);
            const int e7   = 63 - col0 - 7;          // multiple of 8, in [0,56]
            const int eb   = e7 >> 3;                // bits select r^8/r^16/r^32
            float pr = 1.f, pi = 0.f;
            {
                float tr, ti;
                CMUL(tr, ti, pr, pi, P8r, P8i);
                pr = (eb & 1) ? tr : pr;  pi = (eb & 1) ? ti : pi;
                CMUL(tr, ti, pr, pi, P16r, P16i);
                pr = (eb & 2) ? tr : pr;  pi = (eb & 2) ? ti : pi;
                CMUL(tr, ti, pr, pi, P32r, P32i);
                pr = (eb & 4) ? tr : pr;  pi = (eb & 4) ? ti : pi;
            }
            short8 pv;
            pv[7] = (short)f2bf(isIm ? pi : pr);
            #pragma unroll
            for (int j = 6; j >= 0; --j) {
                CMUL(pr, pi, pr, pi, R1r, R1i);      // exponent +1 per step
                pv[j] = (short)f2bf(isIm ? pi : pr);
            }
            aP[kh] = pv;
        }
    }

    #pragma unroll
    for (int it = 0; it < 2; ++it) {
        short* Us = it ? UsB : UsA;

        // ---- mm1 (Y1 = H x U) + mm2 (E = P x U), A-frags from regs ----
        f32x4 accY[4], accE[4];
        #pragma unroll
        for (int nt = 0; nt < 4; ++nt) {
            accY[nt] = (f32x4){0.f, 0.f, 0.f, 0.f};
            accE[nt] = (f32x4){0.f, 0.f, 0.f, 0.f};
        }
        #pragma unroll
        for (int kh = 0; kh < 2; ++kh) {
            const int k0 = kh << 5;
            #pragma unroll
            for (int nt = 0; nt < 4; ++nt) {
                const short8 bU = *(const short8*)&Us[((nt << 4) + rowi) * STR + k0 + (quad << 3)];
                accY[nt] = __builtin_amdgcn_mfma_f32_16x16x32_bf16(aH[kh], bU, accY[nt], 0, 0, 0);
                accE[nt] = __builtin_amdgcn_mfma_f32_16x16x32_bf16(aP[kh], bU, accE[nt], 0, 0, 0);
            }
        }

        // ---- write E planar into dedicated Em (no aliasing hazard) ----
        #pragma unroll
        for (int nt = 0; nt < 4; ++nt) {
            uint2 pk;
            pk.x = (unsigned)f2bf(accE[nt][0]) | ((unsigned)f2bf(accE[nt][1]) << 16);
            pk.y = (unsigned)f2bf(accE[nt][2]) | ((unsigned)f2bf(accE[nt][3]) << 16);
            *(uint2*)&Em[((nt << 4) + rowi) * STR + m0 + (quad << 2)] = pk;
        }

        // ---- drain tile1 prefetch into UsB (covered by tile0 compute) ----
        if (it == 0) {
            #pragma unroll
            for (int jj = 0; jj < 4; ++jj) {
                const int v  = tid + (jj << 8);
                const int c  = v >> 4;
                const int t0 = (v & 15) << 2;
                uint2 pk;
                pk.x = (unsigned)f2bf(v1[jj].x) | ((unsigned)f2bf(v1[jj].y) << 16);
                pk.y = (unsigned)f2bf(v1[jj].z) | ((unsigned)f2bf(v1[jj].w) << 16);
                *(uint2*)&UsB[c * STR + t0] = pk;
            }
        }
        __syncthreads();                           // B_E: E ready (UsB staged)

        // ---- scan phase a: thread (d,g) owns chunks 8g..8g+7 ----
        const int cb = g << 3;
        float Er[8], Ei[8];
        {
            float Sr = 0.f, Si = 0.f;
            #pragma unroll
            for (int i = 0; i < 8; ++i) {
                const int c = cb + i;
                Er[i] = bf2f((unsigned short)Em[c * STR + d]);
                Ei[i] = bf2f((unsigned short)Em[c * STR + 32 + d]);
                const float nr = fmaf(Ar, Sr, fmaf(-Ai, Si, Er[i]));
                const float ni = fmaf(Ar, Si, fmaf(Ai, Sr, Ei[i]));
                Sr = nr; Si = ni;
            }
            Seg[d * 18 + (g << 1)]     = Sr;
            Seg[d * 18 + (g << 1) + 1] = Si;
        }
        __syncthreads();                           // B_Seg: Seg ready

        // ---- scan phase c: combine + emit Q (into EQ; Rmat reads long done) ----
        {
            float offr = 0.f, offi = 0.f;
            #pragma unroll
            for (int gp = 0; gp < 7; ++gp) {
                const float2 sg = *(const float2*)&Seg[d * 18 + (gp << 1)];
                const float nr = fmaf(S8r, offr, fmaf(-S8i, offi, sg.x));
                const float ni = fmaf(S8r, offi, fmaf(S8i, offr, sg.y));
                const bool take = gp < g;
                offr = take ? nr : offr;
                offi = take ? ni : offi;
            }
            float Gr = vv, Gi = 0.f;               // v * A^(8g)
            if (g & 1) { float nr, ni; CMUL(nr, ni, Gr, Gi, S8r, S8i);   Gr = nr; Gi = ni; }
            if (g & 2) { float nr, ni; CMUL(nr, ni, Gr, Gi, S16r, S16i); Gr = nr; Gi = ni; }
            if (g & 4) { float nr, ni; CMUL(nr, ni, Gr, Gi, S32r, S32i); Gr = nr; Gi = ni; }
            float Sr = offr, Si = offi;
            #pragma unroll
            for (int i = 0; i < 8; ++i) {
                const int c = cb + i;
                const float Qr = fmaf(wrr, Sr, fmaf(-wri, Si, Gr));
                const float Qi = fmaf(wrr, Si, fmaf(wri, Sr, Gi));
                EQ[c * STR + d]      = (short)f2bf(Qr);
                EQ[c * STR + 32 + d] = (short)f2bf(Qi);
                const float nr = fmaf(Ar, Sr, fmaf(-Ai, Si, Er[i]));
                const float ni = fmaf(Ar, Si, fmaf(Ai, Sr, Ei[i]));
                Sr = nr; Si = ni;
                float nGr, nGi;
                CMUL(nGr, nGi, Ar, Ai, Gr, Gi);
                Gr = nGr; Gi = nGi;
            }
        }
        __syncthreads();                           // B_Q: Q ready

        // ---- mm3: Y += R x Q ----
        #pragma unroll
        for (int kh = 0; kh < 2; ++kh) {
            const int k0 = kh << 5;
            #pragma unroll
            for (int nt = 0; nt < 4; ++nt) {
                const short8 bQ = *(const short8*)&EQ[((nt << 4) + rowi) * STR + k0 + (quad << 3)];
                accY[nt] = __builtin_amdgcn_mfma_f32_16x16x32_bf16(aR[kh], bQ, accY[nt], 0, 0, 0);
            }
        }

        // ---- epilogue: += D*u (from LDS tile), float4 stores ----
        float* op = out + ((((size_t)(bp * 2 + it) * HH) + hh) << 12);
        #pragma unroll
        for (int nt = 0; nt < 4; ++nt) {
            const int c    = (nt << 4) + rowi;
            const int toff = m0 + (quad << 2);
            const uint2 uu = *(const uint2*)&Us[c * STR + toff];
            float4 res;
            res.x = fmaf(Dh, bf2f((unsigned short)(uu.x & 0xffffu)), accY[nt][0]);
            res.y = fmaf(Dh, bf2f((unsigned short)(uu.x >> 16)),     accY[nt][1]);
            res.z = fmaf(Dh, bf2f((unsigned short)(uu.y & 0xffffu)), accY[nt][2]);
            res.w = fmaf(Dh, bf2f((unsigned short)(uu.y >> 16)),     accY[nt][3]);
            *(float4*)&op[c * 64 + toff] = res;
        }
        // no trailing barrier: next-tile writes target Em/Seg/EQ, each of
        // which is separated from this tile's readers by B_E/B_Seg of it=1.
    }
}

extern "C" void kernel_launch(void* const* d_in, const int* in_sizes, int n_in,
                              void* d_out, int out_size, void* d_ws, size_t ws_size,
                              hipStream_t stream) {
    const float* u     = (const float*)d_in[0];
    const float* theta = (const float*)d_in[1];
    const float* a     = (const float*)d_in[2];
    const float* Dp    = (const float*)d_in[3];
    const float* b_p   = (const float*)d_in[4];
    const float* c_p   = (const float*)d_in[5];
    const float* x0    = (const float*)d_in[6];
    float* out = (float*)d_out;
    (void)d_ws; (void)ws_size;

    hipLaunchKernelGGL(s4_fused_kernel, dim3(HH * 4), dim3(256), 0, stream,
                       u, theta, a, Dp, b_p, c_p, x0, out);
}